// Round 10
// baseline (163.183 us; speedup 1.0000x reference)
//
#include <hip/hip_runtime.h>

// GraphSNN: per-node MLP (13->16->8->8, relu each layer) -> segment_sum over
// dag ids (20k dags) -> per-dag MLP (8->16->8->8, relu each layer) -> sum.
// Output: [num_dags*8] dag_summ ++ [8] global_summ, fp32.
//
// Round 10: r9 structure (K1 coalesced-tile MLP: validated, 97->43us;
// K3 validated). K2 rebuilt for memory-level parallelism — r9 counters
// showed it latency-bound (VALU 2.8%, HBM 10%, occ 43%): one serial
// idx->s->atomic chain per thread. Changes, K2 only:
//  - 8 independent nodes per thread per iteration: all idx loads issued,
//    then all s-row float4 loads, then atomics (16 loads in flight/thread)
//  - acc rows padded to stride 9 (ds_add banks were (d*8+j)%32 = 4 values
//    -> up to 16-way conflict); un-padded at flush, K3 layout unchanged
//  - DPP 4400 (158.4 KB LDS), 5 partitions x 52 chunks = 260 blocks

#define TILE   256    // nodes per K1 block
#define DPP    4400   // dags per partition; acc = 4400*9*4 = 158,400 B
#define NCHUNK 52     // node chunks; 5 partitions * 52 = 260 blocks
#define NTHR2  1024
#define KB     8      // nodes batched per thread in K2

// LDS weight layout (float offsets)
#define OW0 0
#define OB0 208
#define OW1 224
#define OB1 352
#define OW2 360
#define OB2 424

// ---------------------------------------------------------------- K1
// (r9-validated: coalesced tile staging + LDS float4 weights)
extern "C" __global__ void __launch_bounds__(256) gsnn_node_mlp2(
    const float* __restrict__ inputs,
    const float* __restrict__ w0, const float* __restrict__ b0,
    const float* __restrict__ w1, const float* __restrict__ b1,
    const float* __restrict__ w2, const float* __restrict__ b2,
    float* __restrict__ s_out,
    int n_nodes)
{
    __shared__ float xs[TILE * 13];   // 13,312 B
    __shared__ float wl[432];         //  1,728 B

    const int tid = threadIdx.x;

    for (int i = tid; i < 432; i += 256) {
        float v;
        if      (i < 208) v = w0[i];
        else if (i < 224) v = b0[i - 208];
        else if (i < 352) v = w1[i - 224];
        else if (i < 360) v = b1[i - 352];
        else if (i < 424) v = w2[i - 360];
        else              v = b2[i - 424];
        wl[i] = v;
    }

    const long long base   = (long long)blockIdx.x * TILE;
    const int       nvalid = (int)min((long long)TILE, (long long)n_nodes - base);

    // ---- stage tile: fully coalesced ----
    if (nvalid == TILE) {
        const float4* g4 = (const float4*)(inputs + base * 13);
        float4*       l4 = (float4*)xs;
        #pragma unroll
        for (int j = 0; j < 4; ++j) {
            const int i = tid + j * 256;
            if (i < 832) l4[i] = g4[i];
        }
    } else {
        for (int i = tid; i < nvalid * 13; i += 256)
            xs[i] = inputs[base * 13 + i];
    }
    __syncthreads();

    if (tid >= nvalid) return;

    float x[13];
    #pragma unroll
    for (int k = 0; k < 13; ++k) x[k] = xs[tid * 13 + k];

    const float4* w0v = (const float4*)(wl + OW0);
    const float4* b0v = (const float4*)(wl + OB0);
    const float4* w1v = (const float4*)(wl + OW1);
    const float4* b1v = (const float4*)(wl + OB1);
    const float4* w2v = (const float4*)(wl + OW2);
    const float4* b2v = (const float4*)(wl + OB2);

    float h0[16];
    #pragma unroll
    for (int j4 = 0; j4 < 4; ++j4) {
        const float4 b = b0v[j4];
        h0[j4*4+0]=b.x; h0[j4*4+1]=b.y; h0[j4*4+2]=b.z; h0[j4*4+3]=b.w;
    }
    #pragma unroll
    for (int k = 0; k < 13; ++k) {
        const float xv = x[k];
        #pragma unroll
        for (int j4 = 0; j4 < 4; ++j4) {
            const float4 w = w0v[k*4 + j4];
            h0[j4*4+0] = fmaf(xv, w.x, h0[j4*4+0]);
            h0[j4*4+1] = fmaf(xv, w.y, h0[j4*4+1]);
            h0[j4*4+2] = fmaf(xv, w.z, h0[j4*4+2]);
            h0[j4*4+3] = fmaf(xv, w.w, h0[j4*4+3]);
        }
    }
    #pragma unroll
    for (int i = 0; i < 16; ++i) h0[i] = fmaxf(h0[i], 0.f);

    float h1[8];
    #pragma unroll
    for (int j4 = 0; j4 < 2; ++j4) {
        const float4 b = b1v[j4];
        h1[j4*4+0]=b.x; h1[j4*4+1]=b.y; h1[j4*4+2]=b.z; h1[j4*4+3]=b.w;
    }
    #pragma unroll
    for (int k = 0; k < 16; ++k) {
        const float xv = h0[k];
        #pragma unroll
        for (int j4 = 0; j4 < 2; ++j4) {
            const float4 w = w1v[k*2 + j4];
            h1[j4*4+0] = fmaf(xv, w.x, h1[j4*4+0]);
            h1[j4*4+1] = fmaf(xv, w.y, h1[j4*4+1]);
            h1[j4*4+2] = fmaf(xv, w.z, h1[j4*4+2]);
            h1[j4*4+3] = fmaf(xv, w.w, h1[j4*4+3]);
        }
    }
    #pragma unroll
    for (int i = 0; i < 8; ++i) h1[i] = fmaxf(h1[i], 0.f);

    float h2[8];
    #pragma unroll
    for (int j4 = 0; j4 < 2; ++j4) {
        const float4 b = b2v[j4];
        h2[j4*4+0]=b.x; h2[j4*4+1]=b.y; h2[j4*4+2]=b.z; h2[j4*4+3]=b.w;
    }
    #pragma unroll
    for (int k = 0; k < 8; ++k) {
        const float xv = h1[k];
        #pragma unroll
        for (int j4 = 0; j4 < 2; ++j4) {
            const float4 w = w2v[k*2 + j4];
            h2[j4*4+0] = fmaf(xv, w.x, h2[j4*4+0]);
            h2[j4*4+1] = fmaf(xv, w.y, h2[j4*4+1]);
            h2[j4*4+2] = fmaf(xv, w.z, h2[j4*4+2]);
            h2[j4*4+3] = fmaf(xv, w.w, h2[j4*4+3]);
        }
    }

    float4 o0, o1;
    o0.x = fmaxf(h2[0],0.f); o0.y = fmaxf(h2[1],0.f);
    o0.z = fmaxf(h2[2],0.f); o0.w = fmaxf(h2[3],0.f);
    o1.x = fmaxf(h2[4],0.f); o1.y = fmaxf(h2[5],0.f);
    o1.z = fmaxf(h2[6],0.f); o1.w = fmaxf(h2[7],0.f);
    float4* out4 = (float4*)(s_out + (base + tid) * 8);
    out4[0] = o0; out4[1] = o1;
}

// ---------------------------------------------------------------- K2
// batched-MLP scan: KB independent nodes per thread per iteration
extern "C" __global__ void __launch_bounds__(NTHR2) gsnn_seg_partial2(
    const int*   __restrict__ node_to_dag,
    const float* __restrict__ s,
    float*       __restrict__ partials,   // [npart*NCHUNK][DPP*8]
    int n_nodes, int num_dags, int chunk)
{
    __shared__ float acc[DPP * 9];        // 158,400 B (stride-9 rows)

    const int tid = threadIdx.x;
    const int p   = blockIdx.x / NCHUNK;  // dag partition
    const int c   = blockIdx.x % NCHUNK;  // node chunk

    for (int i = tid; i < DPP * 9; i += NTHR2) acc[i] = 0.f;
    __syncthreads();

    const int lo = p * DPP;
    const int hi = min(lo + DPP, num_dags);

    const long long nb = (long long)c * chunk;
    const long long ne = min(nb + (long long)chunk, (long long)n_nodes);

    for (long long base = nb; base < ne; base += (long long)NTHR2 * KB) {
        int dd[KB];
        // 1) issue all idx loads (independent, coalesced)
        #pragma unroll
        for (int k = 0; k < KB; ++k) {
            const long long i = base + tid + (long long)k * NTHR2;
            dd[k] = (i < ne) ? node_to_dag[i] : -1;
        }
        // 2) issue all in-range s-row loads (up to 2*KB float4 in flight)
        float4 ra[KB], rb[KB];
        #pragma unroll
        for (int k = 0; k < KB; ++k) {
            if (dd[k] >= lo && dd[k] < hi) {
                const long long i = base + tid + (long long)k * NTHR2;
                const float4* r = (const float4*)(s + i * 8);
                ra[k] = r[0]; rb[k] = r[1];
            }
        }
        // 3) LDS accumulate (stride-9 rows -> conflict-free banks)
        #pragma unroll
        for (int k = 0; k < KB; ++k) {
            if (dd[k] >= lo && dd[k] < hi) {
                float* dst = acc + (size_t)(dd[k] - lo) * 9;
                atomicAdd(dst + 0, ra[k].x); atomicAdd(dst + 1, ra[k].y);
                atomicAdd(dst + 2, ra[k].z); atomicAdd(dst + 3, ra[k].w);
                atomicAdd(dst + 4, rb[k].x); atomicAdd(dst + 5, rb[k].y);
                atomicAdd(dst + 6, rb[k].z); atomicAdd(dst + 7, rb[k].w);
            }
        }
    }
    __syncthreads();

    // flush: un-pad stride-9 -> dense [DPP*8] (K3's validated layout)
    float4* out4 = (float4*)(partials + (size_t)blockIdx.x * (DPP * 8));
    for (int f = tid; f < DPP * 2; f += NTHR2) {
        const int row = f >> 1, j0 = (f & 1) << 2;
        const float* a = acc + row * 9 + j0;
        float4 vv; vv.x = a[0]; vv.y = a[1]; vv.z = a[2]; vv.w = a[3];
        out4[f] = vv;
    }
}

// ---------------------------------------------------------------- K3
// (validated structure; DPP/NCHUNK via macros)
extern "C" __global__ void __launch_bounds__(256) gsnn_dag_finish(
    const float* __restrict__ partials,
    const float* __restrict__ w0, const float* __restrict__ b0,
    const float* __restrict__ w1, const float* __restrict__ b1,
    const float* __restrict__ w2, const float* __restrict__ b2,
    float* __restrict__ dag_summ,
    float* __restrict__ global_out,
    int num_dags)
{
    __shared__ float4 w0s[32];   // [8][16] as [k*4 + j4]
    __shared__ float4 b0s[4];
    __shared__ float4 w1s[32];   // [16][8] as [k*2 + j4]
    __shared__ float4 b1s[2];
    __shared__ float4 w2s[16];   // [8][8]  as [k*2 + j4]
    __shared__ float4 b2s[2];
    __shared__ float  gsum_s[8];

    const int tid = threadIdx.x;
    {
        float* p;
        p = (float*)w0s; for (int i = tid; i < 128; i += 256) p[i] = w0[i];
        p = (float*)w1s; for (int i = tid; i < 128; i += 256) p[i] = w1[i];
        p = (float*)w2s; if (tid < 64) p[tid] = w2[tid];
        p = (float*)b0s; if (tid < 16) p[tid] = b0[tid];
        p = (float*)b1s; if (tid < 8)  p[tid] = b1[tid];
        p = (float*)b2s; if (tid < 8)  p[tid] = b2[tid];
    }
    if (tid < 8) gsum_s[tid] = 0.f;
    __syncthreads();

    const int d = blockIdx.x * 256 + tid;

    float h2[8] = {0.f,0.f,0.f,0.f,0.f,0.f,0.f,0.f};
    if (d < num_dags) {
        const int p_  = d / DPP;
        const int loc = d - p_ * DPP;
        float x[8] = {0.f,0.f,0.f,0.f,0.f,0.f,0.f,0.f};
        #pragma unroll 4
        for (int cc = 0; cc < NCHUNK; ++cc) {
            const float4* r = (const float4*)(partials +
                ((size_t)(p_ * NCHUNK + cc) * DPP + loc) * 8);
            const float4 a = r[0], b = r[1];
            x[0]+=a.x; x[1]+=a.y; x[2]+=a.z; x[3]+=a.w;
            x[4]+=b.x; x[5]+=b.y; x[6]+=b.z; x[7]+=b.w;
        }
        {   // write dag_summ row
            float4 o0, o1;
            o0.x=x[0]; o0.y=x[1]; o0.z=x[2]; o0.w=x[3];
            o1.x=x[4]; o1.y=x[5]; o1.z=x[6]; o1.w=x[7];
            float4* out4 = (float4*)(dag_summ + (size_t)d * 8);
            out4[0] = o0; out4[1] = o1;
        }

        float h0[16];
        #pragma unroll
        for (int j4 = 0; j4 < 4; ++j4) {
            const float4 b = b0s[j4];
            h0[j4*4+0]=b.x; h0[j4*4+1]=b.y; h0[j4*4+2]=b.z; h0[j4*4+3]=b.w;
        }
        #pragma unroll
        for (int k = 0; k < 8; ++k) {
            #pragma unroll
            for (int j4 = 0; j4 < 4; ++j4) {
                const float4 w = w0s[k*4 + j4];
                h0[j4*4+0] = fmaf(x[k], w.x, h0[j4*4+0]);
                h0[j4*4+1] = fmaf(x[k], w.y, h0[j4*4+1]);
                h0[j4*4+2] = fmaf(x[k], w.z, h0[j4*4+2]);
                h0[j4*4+3] = fmaf(x[k], w.w, h0[j4*4+3]);
            }
        }
        #pragma unroll
        for (int i = 0; i < 16; ++i) h0[i] = fmaxf(h0[i], 0.f);

        float h1[8];
        #pragma unroll
        for (int j4 = 0; j4 < 2; ++j4) {
            const float4 b = b1s[j4];
            h1[j4*4+0]=b.x; h1[j4*4+1]=b.y; h1[j4*4+2]=b.z; h1[j4*4+3]=b.w;
        }
        #pragma unroll
        for (int k = 0; k < 16; ++k) {
            #pragma unroll
            for (int j4 = 0; j4 < 2; ++j4) {
                const float4 w = w1s[k*2 + j4];
                h1[j4*4+0] = fmaf(h0[k], w.x, h1[j4*4+0]);
                h1[j4*4+1] = fmaf(h0[k], w.y, h1[j4*4+1]);
                h1[j4*4+2] = fmaf(h0[k], w.z, h1[j4*4+2]);
                h1[j4*4+3] = fmaf(h0[k], w.w, h1[j4*4+3]);
            }
        }
        #pragma unroll
        for (int i = 0; i < 8; ++i) h1[i] = fmaxf(h1[i], 0.f);

        #pragma unroll
        for (int j4 = 0; j4 < 2; ++j4) {
            const float4 b = b2s[j4];
            h2[j4*4+0]=b.x; h2[j4*4+1]=b.y; h2[j4*4+2]=b.z; h2[j4*4+3]=b.w;
        }
        #pragma unroll
        for (int k = 0; k < 8; ++k) {
            #pragma unroll
            for (int j4 = 0; j4 < 2; ++j4) {
                const float4 w = w2s[k*2 + j4];
                h2[j4*4+0] = fmaf(h1[k], w.x, h2[j4*4+0]);
                h2[j4*4+1] = fmaf(h1[k], w.y, h2[j4*4+1]);
                h2[j4*4+2] = fmaf(h1[k], w.z, h2[j4*4+2]);
                h2[j4*4+3] = fmaf(h1[k], w.w, h2[j4*4+3]);
            }
        }
        #pragma unroll
        for (int i = 0; i < 8; ++i) h2[i] = fmaxf(h2[i], 0.f);
    }

    #pragma unroll
    for (int j = 0; j < 8; ++j) {
        float v = h2[j];
        for (int off = 32; off > 0; off >>= 1) v += __shfl_down(v, off);
        if ((tid & 63) == 0) atomicAdd(&gsum_s[j], v);
    }
    __syncthreads();
    if (tid < 8) atomicAdd(global_out + tid, gsum_s[tid]);
}

// ---------------------------------------------------------------- fallbacks
extern "C" __global__ void __launch_bounds__(256) gsnn_node_atomic(
    const float* __restrict__ inputs,
    const int*   __restrict__ node_to_dag,
    const float* __restrict__ w0, const float* __restrict__ b0,
    const float* __restrict__ w1, const float* __restrict__ b1,
    const float* __restrict__ w2, const float* __restrict__ b2,
    float* __restrict__ dag_out,
    int n_nodes)
{
    const long long i = (long long)blockIdx.x * 256 + threadIdx.x;
    if (i >= n_nodes) return;
    float x[13];
    #pragma unroll
    for (int k = 0; k < 13; ++k) x[k] = inputs[i*13 + k];
    float h0[16];
    #pragma unroll
    for (int j = 0; j < 16; ++j) h0[j] = b0[j];
    #pragma unroll
    for (int k = 0; k < 13; ++k)
        #pragma unroll
        for (int j = 0; j < 16; ++j) h0[j] = fmaf(x[k], w0[k*16+j], h0[j]);
    #pragma unroll
    for (int j = 0; j < 16; ++j) h0[j] = fmaxf(h0[j], 0.f);
    float h1[8];
    #pragma unroll
    for (int j = 0; j < 8; ++j) h1[j] = b1[j];
    #pragma unroll
    for (int k = 0; k < 16; ++k)
        #pragma unroll
        for (int j = 0; j < 8; ++j) h1[j] = fmaf(h0[k], w1[k*8+j], h1[j]);
    #pragma unroll
    for (int j = 0; j < 8; ++j) h1[j] = fmaxf(h1[j], 0.f);
    float h2[8];
    #pragma unroll
    for (int j = 0; j < 8; ++j) h2[j] = b2[j];
    #pragma unroll
    for (int k = 0; k < 8; ++k)
        #pragma unroll
        for (int j = 0; j < 8; ++j) h2[j] = fmaf(h1[k], w2[k*8+j], h2[j]);
    float* dst = dag_out + (long long)node_to_dag[i] * 8;
    #pragma unroll
    for (int j = 0; j < 8; ++j) atomicAdd(dst + j, fmaxf(h2[j], 0.f));
}

extern "C" __global__ void __launch_bounds__(256) gsnn_dag_plain(
    const float* __restrict__ dag_summ,
    const float* __restrict__ w0, const float* __restrict__ b0,
    const float* __restrict__ w1, const float* __restrict__ b1,
    const float* __restrict__ w2, const float* __restrict__ b2,
    float* __restrict__ global_out,
    int num_dags)
{
    __shared__ float gsum_s[8];
    const int tid = threadIdx.x;
    if (tid < 8) gsum_s[tid] = 0.f;
    __syncthreads();
    const int d = blockIdx.x * 256 + tid;
    float h2[8] = {0.f,0.f,0.f,0.f,0.f,0.f,0.f,0.f};
    if (d < num_dags) {
        float x[8];
        #pragma unroll
        for (int j = 0; j < 8; ++j) x[j] = dag_summ[(size_t)d*8 + j];
        float h0[16];
        #pragma unroll
        for (int j = 0; j < 16; ++j) h0[j] = b0[j];
        #pragma unroll
        for (int k = 0; k < 8; ++k)
            #pragma unroll
            for (int j = 0; j < 16; ++j) h0[j] = fmaf(x[k], w0[k*16+j], h0[j]);
        #pragma unroll
        for (int j = 0; j < 16; ++j) h0[j] = fmaxf(h0[j], 0.f);
        float h1[8];
        #pragma unroll
        for (int j = 0; j < 8; ++j) h1[j] = b1[j];
        #pragma unroll
        for (int k = 0; k < 16; ++k)
            #pragma unroll
            for (int j = 0; j < 8; ++j) h1[j] = fmaf(h0[k], w1[k*8+j], h1[j]);
        #pragma unroll
        for (int j = 0; j < 8; ++j) h1[j] = fmaxf(h1[j], 0.f);
        #pragma unroll
        for (int j = 0; j < 8; ++j) h2[j] = b2[j];
        #pragma unroll
        for (int k = 0; k < 8; ++k)
            #pragma unroll
            for (int j = 0; j < 8; ++j) h2[j] = fmaf(h1[k], w2[k*8+j], h2[j]);
        #pragma unroll
        for (int j = 0; j < 8; ++j) h2[j] = fmaxf(h2[j], 0.f);
    }
    #pragma unroll
    for (int j = 0; j < 8; ++j) {
        float v = h2[j];
        for (int off = 32; off > 0; off >>= 1) v += __shfl_down(v, off);
        if ((tid & 63) == 0) atomicAdd(&gsum_s[j], v);
    }
    __syncthreads();
    if (tid < 8) atomicAdd(global_out + tid, gsum_s[tid]);
}

extern "C" void kernel_launch(void* const* d_in, const int* in_sizes, int n_in,
                              void* d_out, int out_size, void* d_ws, size_t ws_size,
                              hipStream_t stream) {
    const float* inputs      = (const float*)d_in[0];
    const int*   node_to_dag = (const int*)  d_in[1];
    const float* dw0 = (const float*)d_in[3];
    const float* db0 = (const float*)d_in[4];
    const float* dw1 = (const float*)d_in[5];
    const float* db1 = (const float*)d_in[6];
    const float* dw2 = (const float*)d_in[7];
    const float* db2 = (const float*)d_in[8];
    const float* gw0 = (const float*)d_in[9];
    const float* gb0 = (const float*)d_in[10];
    const float* gw1 = (const float*)d_in[11];
    const float* gb1 = (const float*)d_in[12];
    const float* gw2 = (const float*)d_in[13];
    const float* gb2 = (const float*)d_in[14];

    float* out = (float*)d_out;
    const int num_dags = (out_size - 8) / 8;
    const int n_nodes  = in_sizes[0] / 13;
    const int npart    = (num_dags + DPP - 1) / DPP;

    // K2 chunk: multiple of 4 (harmless; keeps geometry regular)
    const int chunk = (((n_nodes + NCHUNK - 1) / NCHUNK) + 3) & ~3;

    const int    nblocks2 = npart * NCHUNK;
    const size_t s_bytes  = (size_t)n_nodes * 8 * sizeof(float);
    const size_t p_bytes  = (size_t)nblocks2 * DPP * 8 * sizeof(float);

    if (ws_size >= s_bytes + p_bytes) {
        float* s_ws     = (float*)d_ws;
        float* partials = (float*)((char*)d_ws + s_bytes);

        // zero only global_summ (dag_summ fully overwritten by K3)
        hipMemsetAsync(out + (size_t)num_dags * 8, 0, 8 * sizeof(float), stream);

        const int grid1 = (n_nodes + TILE - 1) / TILE;
        gsnn_node_mlp2<<<grid1, 256, 0, stream>>>(
            inputs, dw0, db0, dw1, db1, dw2, db2, s_ws, n_nodes);

        gsnn_seg_partial2<<<nblocks2, NTHR2, 0, stream>>>(
            node_to_dag, s_ws, partials, n_nodes, num_dags, chunk);

        gsnn_dag_finish<<<(num_dags + 255) / 256, 256, 0, stream>>>(
            partials, gw0, gb0, gw1, gb1, gw2, gb2,
            out, out + (size_t)num_dags * 8, num_dags);
    } else {
        // fallback: validated atomic path
        hipMemsetAsync(d_out, 0, (size_t)out_size * sizeof(float), stream);
        gsnn_node_atomic<<<(n_nodes + 255) / 256, 256, 0, stream>>>(
            inputs, node_to_dag, dw0, db0, dw1, db1, dw2, db2, out, n_nodes);
        gsnn_dag_plain<<<(num_dags + 255) / 256, 256, 0, stream>>>(
            out, gw0, gb0, gw1, gb1, gw2, gb2,
            out + (size_t)num_dags * 8, num_dags);
    }
}